// Round 10
// baseline (643.980 us; speedup 1.0000x reference)
//
#include <hip/hip_runtime.h>
#include <stdint.h>

typedef unsigned short u16;
typedef __attribute__((ext_vector_type(8))) __bf16 bf16x8;
typedef __attribute__((ext_vector_type(4))) float f32x4;

#define D_EMB 1024
#define NHEAD 16
#define HDIM 64
#define TSEQ 2048
#define NTOK 4096
#define NEG_BIG -1.0e30f

// async global->LDS, 16B per lane; LDS dest = wave-uniform base + lane*16
#define GLD16(lp, gp) __builtin_amdgcn_global_load_lds( \
    (const __attribute__((address_space(1))) unsigned int*)(gp), \
    (__attribute__((address_space(3))) unsigned int*)(lp), 16, 0, 0)

__device__ __forceinline__ float bf2f(u16 u) {
    union { unsigned int i; float f; } c; c.i = ((unsigned int)u) << 16; return c.f;
}
__device__ __forceinline__ u16 f2bf(float f) {
    union { float f; unsigned int i; } c; c.f = f;
    unsigned int r = (c.i + 0x7FFFu + ((c.i >> 16) & 1u)) >> 16;
    return (u16)r;
}
__device__ __forceinline__ void cp16(u16* dst, const u16* src) {
    *reinterpret_cast<uint4*>(dst) = *reinterpret_cast<const uint4*>(src);
}
__device__ __forceinline__ float load_in(const u16* p, size_t idx, int f32) {
    return f32 ? reinterpret_cast<const float*>(p)[idx] : bf2f(p[idx]);
}
// tiled layout index with 16B-slot XOR swizzle baked in:
// T[(row/128)*KB + col/32][row%128][slot^row & 3][col%8], KB = K/32.
// GEMMs stage tiles verbatim (linear) and XOR the slot on fragment reads.
__device__ __forceinline__ size_t tidx(int row, int col, int KB) {
    int c = (col & 7) | ((((col >> 3) ^ row) & 3) << 3);
    return ((size_t)((row >> 7) * KB + (col >> 5)) * 128 + (row & 127)) * 32 + c;
}

// one-time dtype sniff (R4-proven mechanism), hoisted: writes flag to ws
__global__ void detect_kernel(const u16* __restrict__ x, u16* __restrict__ fl) {
    if (threadIdx.x == 0) {
        int f = 0;
        for (int i = 0; i < 128; ++i) {
            float v = fabsf(bf2f(x[i]));
            if (!(v <= 1.0e3f)) f = 1;
        }
        fl[0] = (u16)f;
    }
}

// ---------------- weight prep ----------------
__global__ __launch_bounds__(256) void transpose_tiled_kernel(
        const u16* __restrict__ X, u16* __restrict__ Xt, int KB,
        const u16* __restrict__ fl) {
    __shared__ __align__(16) u16 Ts[64 * 72];
    int f32 = fl[0];
    int bi = blockIdx.y, bj = blockIdx.x;   // bi: k-tile, bj: n-tile
    int NS = gridDim.x * 64;
    int t = threadIdx.x;
    for (int p = 0; p < 2; ++p) {
        int idx = p * 256 + t;
        int row = idx >> 3, col8 = (idx & 7) * 8;
        size_t src = (size_t)(bi * 64 + row) * NS + bj * 64 + col8;
        if (f32) {
            for (int jj = 0; jj < 8; ++jj)
                Ts[row * 72 + col8 + jj] = f2bf(reinterpret_cast<const float*>(X)[src + jj]);
        } else {
            cp16(&Ts[row * 72 + col8], &X[src]);
        }
    }
    __syncthreads();
    for (int p = 0; p < 2; ++p) {
        int idx = p * 256 + t;
        int row = idx >> 3, col8 = (idx & 7) * 8;
        union { u16 u[8]; uint4 v; } tmp;
        for (int jj = 0; jj < 8; ++jj) tmp.u[jj] = Ts[(col8 + jj) * 72 + row];
        int n = bj * 64 + row, k0 = bi * 64 + col8;
        *reinterpret_cast<uint4*>(&Xt[tidx(n, k0, KB)]) = tmp.v;
    }
}

__global__ __launch_bounds__(256) void pack_qkv_kernel(
        const u16* __restrict__ Wq, const u16* __restrict__ Wk,
        const u16* __restrict__ Wv, u16* __restrict__ Wt,
        const u16* __restrict__ fl) {
    int f32 = fl[0];
    int idx = blockIdx.x * 256 + threadIdx.x;   // 3*16*1024*64
    int e = idx & 63, d = (idx >> 6) & 1023, hh = (idx >> 16) & 15, sel = idx >> 20;
    const u16* W = (sel == 0) ? Wq : ((sel == 1) ? Wk : Wv);
    size_t src = (size_t)hh * (D_EMB * HDIM) + (size_t)d * HDIM + e;
    float v = f32 ? reinterpret_cast<const float*>(W)[src] : bf2f(W[src]);
    int n = sel * 1024 + hh * 64 + e;
    Wt[tidx(n, d, 32)] = f2bf(v);
}

// ---------------- layernorm: raw-dtype input -> tiled bf16 (KB=32) ----------------
__global__ __launch_bounds__(256) void ln_kernel(
        const u16* __restrict__ X, const u16* __restrict__ g,
        const u16* __restrict__ be, u16* __restrict__ Ht,
        const u16* __restrict__ fl) {
    int f32 = fl[0];
    int row = blockIdx.x;
    int t = threadIdx.x;
    float v[4];
    float s = 0.f, sq = 0.f;
    for (int i = 0; i < 4; ++i) {
        v[i] = load_in(X, (size_t)row * D_EMB + t + i * 256, f32);
        s += v[i]; sq += v[i] * v[i];
    }
    for (int m = 32; m; m >>= 1) { s += __shfl_down(s, m); sq += __shfl_down(sq, m); }
    __shared__ float red[8];
    int wid = t >> 6, lane = t & 63;
    if (lane == 0) { red[wid] = s; red[wid + 4] = sq; }
    __syncthreads();
    if (t == 0) {
        float S = red[0] + red[1] + red[2] + red[3];
        float SQ = red[4] + red[5] + red[6] + red[7];
        float mean = S * (1.f / 1024.f);
        float var = SQ * (1.f / 1024.f) - mean * mean;
        red[0] = mean; red[1] = rsqrtf(var + 1e-5f);
    }
    __syncthreads();
    float mean = red[0], rstd = red[1];
    for (int i = 0; i < 4; ++i) {
        int c = t + i * 256;
        float hv = (v[i] - mean) * rstd * load_in(g, c, f32) + load_in(be, c, f32);
        Ht[tidx(row, c, 32)] = f2bf(hv);
    }
}

// ---------------- GEMM: async 2-phase K-loop (global_load_lds dbuf, 1 barrier) ---
// flags: 1=relu, 2=out_ext, 4=c_tiled, 8=qkv-split (Q,K rowmajor 2048-wide; V -> C2 transposed planes)
template<int TAG, int TN>
__global__ __launch_bounds__(256) void gemm_t(
        const u16* __restrict__ At, const u16* __restrict__ Bt, u16* __restrict__ C,
        u16* __restrict__ C2,
        const u16* __restrict__ bias, const u16* __restrict__ res,
        int N, int K, int flags, int row_off,
        const u16* __restrict__ fl) {
    constexpr int NF = (TN == 128) ? 4 : 2;       // 16-wide n-frags per wave
    __shared__ __align__(16) u16 As2[2][4096];
    __shared__ __align__(16) u16 Bs2[2][TN * 32];
    int f32 = fl[0];
    int t = threadIdx.x;
    int gx = gridDim.x, gy = gridDim.y;
    int id = blockIdx.y * gx + blockIdx.x;
    int total = gx * gy;
    // XCD swizzle: xcd=id&7 owns 4-wide x th-tall block tiles
    int xcd = id & 7, seq = id >> 3, P = total >> 3;
    int tpb = (P >= 32) ? 32 : 16;
    int th  = (P >= 32) ? 8 : 4;
    int tile = xcd * (P / tpb) + seq / tpb;
    int within = seq % tpb;
    int tiles_x = gx >> 2;
    int bx = (tile % tiles_x) * 4 + (within & 3);
    int by = (tile / tiles_x) * th + (within >> 2);
    int n0 = bx * TN, m0 = by * 128;
    int w = t >> 6, lane = t & 63, quad = lane >> 4, l16 = lane & 15;
    int wm = (TN == 128) ? (w >> 1) * 64 : (w & 1) * 64;
    int wn = (TN == 128) ? (w & 1) * 64  : (w >> 1) * 32;
    int KB = K >> 5;
    int kb0 = (seq * (KB >> 5)) & (KB - 1);       // stagger start (KB pow2)
    const u16* Ab = At + (size_t)(m0 >> 7) * KB * 4096 + w * 512 + lane * 8;
    const u16* Bb = Bt + (size_t)(n0 >> 7) * KB * 4096
                       + ((TN == 64) ? (n0 & 64) * 32 : 0) + w * 512 + lane * 8;

    auto stage = [&](int buf, int kb) {
        const u16* ga = Ab + (size_t)kb * 4096;
        const u16* gb = Bb + (size_t)kb * 4096;
        u16* la = &As2[buf][w * 512];
        u16* lb = &Bs2[buf][w * 512];
        GLD16(la, ga);
        GLD16(la + 2048, ga + 2048);
        GLD16(lb, gb);
        if constexpr (TN == 128) { GLD16(lb + 2048, gb + 2048); }
    };

    const f32x4 fz = {0.f, 0.f, 0.f, 0.f};
    f32x4 acc[4][NF];
    for (int mt = 0; mt < 4; ++mt)
        for (int nt = 0; nt < NF; ++nt) acc[mt][nt] = fz;

    stage(0, kb0);
    __syncthreads();
    int kb = kb0;
    for (int it = 0; it < KB; ++it) {
        int cur = it & 1;
        int kn = (kb + 1 == KB) ? 0 : kb + 1;
        if (it + 1 < KB) stage(cur ^ 1, kn);      // async prefetch during MFMAs
        bf16x8 af[4], bfr[NF];
        for (int mt = 0; mt < 4; ++mt) {
            int r = wm + mt * 16 + l16;
            af[mt] = *reinterpret_cast<const bf16x8*>(
                &As2[cur][r * 32 + (((quad ^ r) & 3) << 3)]);
        }
        for (int nt = 0; nt < NF; ++nt) {
            int r = wn + nt * 16 + l16;
            bfr[nt] = *reinterpret_cast<const bf16x8*>(
                &Bs2[cur][r * 32 + (((quad ^ r) & 3) << 3)]);
        }
        for (int mt = 0; mt < 4; ++mt)
            for (int nt = 0; nt < NF; ++nt)
                acc[mt][nt] = __builtin_amdgcn_mfma_f32_16x16x32_bf16(af[mt], bfr[nt], acc[mt][nt], 0, 0, 0);
        __syncthreads();                          // drains prefetch (vmcnt) + reads
        kb = kn;
    }

    int relu_f = flags & 1, out_ext = flags & 2, c_tiled = flags & 4, qkvsp = flags & 8;
    if (qkvsp) {
        // Q,K -> rowmajor [4096][2048]; V -> transposed planes, 4 consecutive s per thread (8B store)
        for (int mt = 0; mt < 4; ++mt)
            for (int nt = 0; nt < NF; ++nt) {
                int gc = n0 + wn + nt * 16 + l16;
                int grb = m0 + wm + mt * 16 + quad * 4;
                if (gc < 2048) {
                    for (int r = 0; r < 4; ++r)
                        C[(size_t)(grb + r) * 2048 + gc] = f2bf(acc[mt][nt][r]);
                } else {
                    int hh = (gc - 2048) >> 6, d = gc & 63;
                    int bb = grb >> 11, s = grb & 2047;
                    union { u16 u[4]; uint2 v; } pk;
                    for (int r = 0; r < 4; ++r) pk.u[r] = f2bf(acc[mt][nt][r]);
                    *reinterpret_cast<uint2*>(
                        &C2[(((size_t)bb * 16 + hh) * 64 + d) * 2048 + s]) = pk.v;
                }
            }
        return;
    }
    for (int mt = 0; mt < 4; ++mt)
        for (int nt = 0; nt < NF; ++nt)
            for (int r = 0; r < 4; ++r) {
                int gr = m0 + wm + mt * 16 + quad * 4 + r;
                int gc = n0 + wn + nt * 16 + l16;
                float v = acc[mt][nt][r];
                if (bias) v += load_in(bias, gc, f32);
                if (relu_f) v = v > 0.f ? v : 0.f;
                size_t oidx = (size_t)(row_off + gr) * N + gc;
                if (res) v += load_in(res, oidx, f32);
                if (c_tiled)      C[tidx(gr, gc, N >> 5)] = f2bf(v);
                else if (out_ext && f32) reinterpret_cast<float*>(C)[oidx] = v;
                else              C[oidx] = f2bf(v);
            }
}

// ---------------- split-K GEMM (atomic f32 partials), TN-tiled like gemm_t ------
// grid (gx,gy,SK); z-slice k-range [z*KBL*32, (z+1)*KBL*32); KBL pow2.
template<int TAG, int KBL, int TN>
__global__ __launch_bounds__(256) void gemm_sk_t(
        const u16* __restrict__ At, const u16* __restrict__ Bt,
        float* __restrict__ Pp, int N, int K) {
    constexpr int NF = (TN == 128) ? 4 : 2;
    __shared__ __align__(16) u16 As2[2][4096];
    __shared__ __align__(16) u16 Bs2[2][TN * 32];
    int t = threadIdx.x;
    int gx = gridDim.x, gy = gridDim.y;
    int id = blockIdx.y * gx + blockIdx.x;
    int total = gx * gy;
    int xcd = id & 7, seq = id >> 3, P = total >> 3;
    int tpb = (P >= 32) ? 32 : 16;
    int th  = (P >= 32) ? 8 : 4;
    int tile = xcd * (P / tpb) + seq / tpb;
    int within = seq % tpb;
    int tiles_x = gx >> 2;
    int bx = (tile % tiles_x) * 4 + (within & 3);
    int by = (tile / tiles_x) * th + (within >> 2);
    int n0 = bx * TN, m0 = by * 128;
    int w = t >> 6, lane = t & 63, quad = lane >> 4, l16 = lane & 15;
    int wm = (TN == 128) ? (w >> 1) * 64 : (w & 1) * 64;
    int wn = (TN == 128) ? (w & 1) * 64  : (w >> 1) * 32;
    int KB = K >> 5;
    int kstart = blockIdx.z * KBL;
    int rel0 = seq & (KBL - 1);                   // stagger within z-slice
    const u16* Ab = At + (size_t)(m0 >> 7) * KB * 4096 + w * 512 + lane * 8;
    const u16* Bb = Bt + (size_t)(n0 >> 7) * KB * 4096
                       + ((TN == 64) ? (n0 & 64) * 32 : 0) + w * 512 + lane * 8;

    auto stage = [&](int buf, int kb) {
        const u16* ga = Ab + (size_t)kb * 4096;
        const u16* gb = Bb + (size_t)kb * 4096;
        u16* la = &As2[buf][w * 512];
        u16* lb = &Bs2[buf][w * 512];
        GLD16(la, ga);
        GLD16(la + 2048, ga + 2048);
        GLD16(lb, gb);
        if constexpr (TN == 128) { GLD16(lb + 2048, gb + 2048); }
    };

    const f32x4 fz = {0.f, 0.f, 0.f, 0.f};
    f32x4 acc[4][NF];
    for (int mt = 0; mt < 4; ++mt)
        for (int nt = 0; nt < NF; ++nt) acc[mt][nt] = fz;

    stage(0, kstart + rel0);
    __syncthreads();
    for (int it = 0; it < KBL; ++it) {
        int cur = it & 1;
        if (it + 1 < KBL)
            stage(cur ^ 1, kstart + ((rel0 + it + 1) & (KBL - 1)));
        bf16x8 af[4], bfr[NF];
        for (int mt = 0; mt < 4; ++mt) {
            int r = wm + mt * 16 + l16;
            af[mt] = *reinterpret_cast<const bf16x8*>(
                &As2[cur][r * 32 + (((quad ^ r) & 3) << 3)]);
        }
        for (int nt = 0; nt < NF; ++nt) {
            int r = wn + nt * 16 + l16;
            bfr[nt] = *reinterpret_cast<const bf16x8*>(
                &Bs2[cur][r * 32 + (((quad ^ r) & 3) << 3)]);
        }
        for (int mt = 0; mt < 4; ++mt)
            for (int nt = 0; nt < NF; ++nt)
                acc[mt][nt] = __builtin_amdgcn_mfma_f32_16x16x32_bf16(af[mt], bfr[nt], acc[mt][nt], 0, 0, 0);
        __syncthreads();
    }

    for (int mt = 0; mt < 4; ++mt)
        for (int nt = 0; nt < NF; ++nt)
            for (int r = 0; r < 4; ++r) {
                int gr = m0 + wm + mt * 16 + quad * 4 + r;
                int gc = n0 + wn + nt * 16 + l16;
                atomicAdd(&Pp[(size_t)gr * N + gc], acc[mt][nt][r]);
            }
}

__global__ __launch_bounds__(256) void zero_f32_kernel(float* __restrict__ p) {
    const f32x4 fz = {0.f, 0.f, 0.f, 0.f};
    reinterpret_cast<f32x4*>(p)[(size_t)blockIdx.x * 256 + threadIdx.x] = fz;
}

// finalize FFN: out[row_off+r][c] = P[r][c] + b2[c] + out(residual, already stored)
__global__ __launch_bounds__(256) void ffn_fin_kernel(
        const float* __restrict__ Pp, const u16* __restrict__ b2,
        u16* __restrict__ out, int row_off, const u16* __restrict__ fl) {
    int f32 = fl[0];
    size_t i = ((size_t)blockIdx.x * 256 + threadIdx.x) * 4;
    int col = (int)(i & 1023);
    f32x4 pv = *reinterpret_cast<const f32x4*>(Pp + i);
    size_t o = (size_t)row_off * 1024 + i;
    if (f32) {
        float* of = reinterpret_cast<float*>(out);
        f32x4 ov = *reinterpret_cast<f32x4*>(of + o);
        for (int j = 0; j < 4; ++j)
            ov[j] += pv[j] + load_in(b2, col + j, 1);
        *reinterpret_cast<f32x4*>(of + o) = ov;
    } else {
        for (int j = 0; j < 4; ++j) {
            float v = bf2f(out[o + j]) + pv[j] + bf2f(b2[col + j]);
            out[o + j] = f2bf(v);
        }
    }
}

// finalize out-proj: out[r][c] = P[r][c] + bo[c] + x[r][c] (residual from input)
__global__ __launch_bounds__(256) void oproj_fin_kernel(
        const float* __restrict__ Pp, const u16* __restrict__ bo,
        const u16* __restrict__ x, u16* __restrict__ out,
        const u16* __restrict__ fl) {
    int f32 = fl[0];
    size_t i = ((size_t)blockIdx.x * 256 + threadIdx.x) * 4;
    int col = (int)(i & 1023);
    f32x4 pv = *reinterpret_cast<const f32x4*>(Pp + i);
    if (f32) {
        const float* xf = reinterpret_cast<const float*>(x);
        float* of = reinterpret_cast<float*>(out);
        f32x4 ov;
        for (int j = 0; j < 4; ++j)
            ov[j] = xf[i + j] + pv[j] + load_in(bo, col + j, 1);
        *reinterpret_cast<f32x4*>(of + i) = ov;
    } else {
        for (int j = 0; j < 4; ++j) {
            float v = bf2f(x[i + j]) + pv[j] + bf2f(bo[col + j]);
            out[i + j] = f2bf(v);
        }
    }
}

// ---------------- flash attention (pair-balanced + intra-block j-split) ----
// qk: [4096][2048] rowmajor (Q cols 0..1023, K cols 1024..2047)
// vt: [b*16+h][64 d][2048 s] planes (V transposed, by QKV gemm)
// Block = 128 thr (2 waves) owning 16 Q-rows (group g) of column pair
// (H=31-px heavy, px light). wave0: heavy j in [0,16) (mask-free, 16 tiles).
// wave1: light column fully (px+1 tiles) then heavy j in [16,H] (16-px tiles),
// stashes heavy partial (m,l,unnormalized O) in LDS. One barrier; wave0 merges.
// Every block ~17 tile-times -> flat 50% occupancy, zero tail.
__global__ __launch_bounds__(128) void flash_kernel(
        const u16* __restrict__ qk, const u16* __restrict__ vt,
        u16* __restrict__ attn_t) {
    __shared__ __align__(16) u16 Ps[32 * 72];
    __shared__ float Om[16 * 64];
    __shared__ float MLm[32];
    int t = threadIdx.x;
    int px = blockIdx.x & 15, g = blockIdx.x >> 4;   // gridDim.x = 64
    int b = blockIdx.y >> 4, h = blockIdx.y & 15;
    int wid = t >> 6, lane = t & 63, quad = lane >> 4, l16 = lane & 15;
    const size_t seq_base = (size_t)b * TSEQ;
    const u16* vplane = vt + (size_t)(b * 16 + h) * 64 * 2048;
    int H = 31 - px;
    const f32x4 fz = {0.f, 0.f, 0.f, 0.f};

    bf16x8 aq[2];
    float m_run[4], l_run[4];
    f32x4 o[4];

    auto load_q = [&](int tq) {
        for (int kit = 0; kit < 2; ++kit)
            aq[kit] = *reinterpret_cast<const bf16x8*>(
                &qk[(seq_base + tq * 64 + g * 16 + l16) * 2048 + h * 64 + kit * 32 + quad * 8]);
    };
    auto reset = [&]() {
        for (int r = 0; r < 4; ++r) { m_run[r] = NEG_BIG; l_run[r] = 0.f; }
        for (int nt = 0; nt < 4; ++nt) o[nt] = fz;
    };
    auto tile = [&](int tq, int j, int domask) {
        f32x4 sa[4];
        for (int nt = 0; nt < 4; ++nt) sa[nt] = fz;
        for (int kit = 0; kit < 2; ++kit)
            for (int nt = 0; nt < 4; ++nt) {
                bf16x8 bk = *reinterpret_cast<const bf16x8*>(
                    &qk[(seq_base + j * 64 + nt * 16 + l16) * 2048 + 1024 + h * 64 + kit * 32 + quad * 8]);
                sa[nt] = __builtin_amdgcn_mfma_f32_16x16x32_bf16(aq[kit], bk, sa[nt], 0, 0, 0);
            }
        int qbase = tq * 64 + g * 16 + quad * 4;
        int sbase = j * 64 + l16;
        float p_val[4][4];
        for (int r = 0; r < 4; ++r) {
            float sv[4];
            float mx = NEG_BIG;
            for (int nt = 0; nt < 4; ++nt) {
                float xv = sa[nt][r] * 0.03125f;   // D^-0.5 = 1/32
                if (domask && (sbase + nt * 16 > qbase + r)) xv = NEG_BIG;
                sv[nt] = xv;
                mx = fmaxf(mx, xv);
            }
            for (int m = 1; m < 16; m <<= 1) mx = fmaxf(mx, __shfl_xor(mx, m));
            float mnew = fmaxf(m_run[r], mx);
            float alpha = __expf(m_run[r] - mnew);
            m_run[r] = mnew;
            float rs = 0.f;
            for (int nt = 0; nt < 4; ++nt) {
                float pv = __expf(sv[nt] - mnew);
                p_val[nt][r] = pv;
                rs += pv;
            }
            for (int m = 1; m < 16; m <<= 1) rs += __shfl_xor(rs, m);
            l_run[r] = l_run[r] * alpha + rs;
            for (int nt = 0; nt < 4; ++nt) o[nt][r] *= alpha;
        }
        // wave-private Ps stripe: same-wave LDS ordering, no barrier needed
        for (int nt = 0; nt < 4; ++nt)
            for (int r = 0; r < 4; ++r)
                Ps[(wid * 16 + quad * 4 + r) * 72 + nt * 16 + l16] = f2bf(p_val[nt][r]);
        for (int kit = 0; kit < 2; ++kit) {
            bf16x8 ap = *reinterpret_cast<const bf16x8*>(
                &Ps[(wid * 16 + l16) * 72 + kit * 32 + quad * 8]);
            for (int nt = 0; nt < 4; ++nt) {
                bf16x8 bv = *reinterpret_cast<const bf16x8*>(
                    &vplane[(size_t)(nt * 16 + l16) * 2048 + j * 64 + kit * 32 + quad * 8]);
                o[nt] = __builtin_amdgcn_mfma_f32_16x16x32_bf16(ap, bv, o[nt], 0, 0, 0);
            }
        }
    };

    if (wid == 0) {
        // heavy column H, first 16 tiles: j*64+maxcol = 1023 < qbase >= 1024 -> mask-free
        load_q(H);
        reset();
        for (int j = 0; j < 16; ++j) tile(H, j, 0);
    } else {
        // light column px (full, diagonal masked)
        load_q(px);
        reset();
        for (int j = 0; j < px; ++j) tile(px, j, 0);
        tile(px, px, 1);
        for (int nt = 0; nt < 4; ++nt)
            for (int r = 0; r < 4; ++r) {
                int trow = (int)seq_base + px * 64 + g * 16 + quad * 4 + r;
                attn_t[tidx(trow, h * 64 + nt * 16 + l16, 32)] = f2bf(o[nt][r] / l_run[r]);
            }
        // heavy tail j in [16, H] (diagonal masked)
        load_q(H);
        reset();
        for (int j = 16; j < H; ++j) tile(H, j, 0);
        tile(H, H, 1);
        // stash heavy partial (m, l, unnormalized O)
        for (int r = 0; r < 4; ++r) {
            int row = quad * 4 + r;
            if (l16 == 0) { MLm[row] = m_run[r]; MLm[16 + row] = l_run[r]; }
            for (int nt = 0; nt < 4; ++nt)
                Om[row * 64 + nt * 16 + l16] = o[nt][r];
        }
    }
    __syncthreads();
    if (wid == 0) {
        // merge wave1's heavy partial and write heavy output
        for (int r = 0; r < 4; ++r) {
            int row = quad * 4 + r;
            float m1 = MLm[row], l1 = MLm[16 + row];
            float mm = fmaxf(m_run[r], m1);
            float a0 = __expf(m_run[r] - mm), a1 = __expf(m1 - mm);
            float li = 1.f / (a0 * l_run[r] + a1 * l1);
            int trow = (int)seq_base + H * 64 + g * 16 + row;
            for (int nt = 0; nt < 4; ++nt) {
                float val = (a0 * o[nt][r] + a1 * Om[row * 64 + nt * 16 + l16]) * li;
                attn_t[tidx(trow, h * 64 + nt * 16 + l16, 32)] = f2bf(val);
            }
        }
    }
}

// ---------------- launch ----------------
// ws (elems, 1M=1<<20):
//  [ 0, 8M): qk rowmajor [4096][2048] -> after flash: W2t_t [0,4M), a1_t [4,12M)
//  [ 8,12M): vt planes [32][64][2048] (V transposed) -> dead after flash
//  [12,16M): h_t -> attn_t -> h2_t
//  [16,20M): Wtq_t [16,19M) -> Wot_t [16,17M) -> W1t_t [16,20M)
//  [20M]:    dtype flag (1 elem)
//  [21,29M): split-K f32 partials -- only if ws_size >= 58MB
extern "C" void kernel_launch(void* const* d_in, const int* in_sizes, int n_in,
                              void* d_out, int out_size, void* d_ws, size_t ws_size,
                              hipStream_t stream) {
    const u16* x   = (const u16*)d_in[0];
    const u16* Wq  = (const u16*)d_in[1];
    const u16* Wk  = (const u16*)d_in[2];
    const u16* Wv  = (const u16*)d_in[3];
    const u16* Wo  = (const u16*)d_in[4];
    const u16* bo  = (const u16*)d_in[5];
    const u16* W1  = (const u16*)d_in[6];
    const u16* b1  = (const u16*)d_in[7];
    const u16* W2  = (const u16*)d_in[8];
    const u16* b2  = (const u16*)d_in[9];
    const u16* g1  = (const u16*)d_in[10];
    const u16* be1 = (const u16*)d_in[11];
    const u16* g2  = (const u16*)d_in[12];
    const u16* be2 = (const u16*)d_in[13];
    u16* out = (u16*)d_out;

    const size_t M1 = (size_t)1 << 20;
    u16* ws    = (u16*)d_ws;
    u16* qk    = ws;               // 8M rowmajor [4096][2048]
    u16* vt    = ws + 8 * M1;      // 4M transposed V planes
    u16* W2t   = ws;               // 4M  (after flash)
    u16* a1    = ws + 4 * M1;      // 8M  tiled, per 2048-row chunk
    u16* h     = ws + 12 * M1;     // 4M  tiled
    u16* attn  = ws + 12 * M1;     // 4M  tiled (after QKV gemm)
    u16* h2    = ws + 12 * M1;     // 4M  tiled (after outproj)
    u16* Wtq   = ws + 16 * M1;     // 3M  tiled
    u16* Wot   = ws + 16 * M1;     // 1M  tiled (after QKV gemm)
    u16* W1t   = ws + 16 * M1;     // 4M  tiled (after outproj)
    u16* fl    = ws + 20 * M1;     // dtype flag
    float* Pp  = reinterpret_cast<float*>(ws + 21 * M1);   // up to 4M f32 partials
    bool sk = ws_size >= ((size_t)58 << 20);

    detect_kernel<<<1, 64, 0, stream>>>(x, fl);

    // LN1 + QKV projection (Q,K rowmajor 2048-wide; V -> vt transposed planes)
    pack_qkv_kernel<<<(3 * 16 * 1024 * 64) / 256, 256, 0, stream>>>(Wq, Wk, Wv, Wtq, fl);
    ln_kernel<<<NTOK, 256, 0, stream>>>(x, g1, be1, h, fl);
    gemm_t<0, 64><<<dim3(48, 32), 256, 0, stream>>>(
        h, Wtq, qk, vt, nullptr, nullptr, 3072, 1024, 8, 0, fl);

    // Wo repack (Wtq dead)
    transpose_tiled_kernel<<<dim3(16, 16), 256, 0, stream>>>(Wo, Wot, 32, fl);

    // attention: qk/vt -> attn_t (tiled); pair-balanced + j-split, 2048 blocks
    flash_kernel<<<dim3(64, 32), 128, 0, stream>>>(qk, vt, attn);

    // out-proj + bias + residual(x) -> d_out; TN=64 sk -> 2048 blocks
    if (sk) {
        zero_f32_kernel<<<4096, 256, 0, stream>>>(Pp);
        gemm_sk_t<2, 8, 64><<<dim3(16, 32, 4), 256, 0, stream>>>(attn, Wot, Pp, 1024, 1024);
        oproj_fin_kernel<<<4096, 256, 0, stream>>>(Pp, bo, x, out, fl);
    } else {
        gemm_t<1, 128><<<dim3(8, 32), 256, 0, stream>>>(
            attn, Wot, out, nullptr, bo, x, 1024, 1024, 2, 0, fl);
    }

    // W2 repack (qk dead), W1 repack (Wot dead), LN2 from d_out (attn dead)
    transpose_tiled_kernel<<<dim3(16, 64), 256, 0, stream>>>(W2, W2t, 128, fl);
    transpose_tiled_kernel<<<dim3(64, 16), 256, 0, stream>>>(W1, W1t, 32, fl);
    ln_kernel<<<NTOK, 256, 0, stream>>>(out, g2, be2, h2, fl);

    // FFN chunk 0 (up: TN=64, 1024 blocks; down: TN=64 sk -> 1024 blocks)
    gemm_t<2, 64><<<dim3(64, 16), 256, 0, stream>>>(
        h2, W1t, a1, nullptr, b1, nullptr, 4096, 1024, 1 | 4, 0, fl);
    if (sk) {
        zero_f32_kernel<<<2048, 256, 0, stream>>>(Pp);
        gemm_sk_t<0, 32, 64><<<dim3(16, 16, 4), 256, 0, stream>>>(a1, W2t, Pp, 1024, 4096);
        ffn_fin_kernel<<<2048, 256, 0, stream>>>(Pp, b2, out, 0, fl);
    } else {
        gemm_t<4, 128><<<dim3(8, 16), 256, 0, stream>>>(
            a1, W2t, out, nullptr, b2, out, 1024, 4096, 2, 0, fl);
    }
    // FFN chunk 1
    gemm_t<3, 64><<<dim3(64, 16), 256, 0, stream>>>(
        h2 + (size_t)2 * M1, W1t, a1, nullptr, b1, nullptr, 4096, 1024, 1 | 4, 0, fl);
    if (sk) {
        zero_f32_kernel<<<2048, 256, 0, stream>>>(Pp);
        gemm_sk_t<1, 32, 64><<<dim3(16, 16, 4), 256, 0, stream>>>(a1, W2t, Pp, 1024, 4096);
        ffn_fin_kernel<<<2048, 256, 0, stream>>>(Pp, b2, out, 2048, fl);
    } else {
        gemm_t<5, 128><<<dim3(8, 16), 256, 0, stream>>>(
            a1, W2t, out, nullptr, b2, out, 1024, 4096, 2, 2048, fl);
    }
}

// Round 11
// 614.273 us; speedup vs baseline: 1.0484x; 1.0484x over previous
//
#include <hip/hip_runtime.h>
#include <stdint.h>

typedef unsigned short u16;
typedef __attribute__((ext_vector_type(8))) __bf16 bf16x8;
typedef __attribute__((ext_vector_type(4))) float f32x4;

#define D_EMB 1024
#define NHEAD 16
#define HDIM 64
#define TSEQ 2048
#define NTOK 4096
#define NEG_BIG -1.0e30f

// async global->LDS, 16B per lane; LDS dest = wave-uniform base + lane*16
#define GLD16(lp, gp) __builtin_amdgcn_global_load_lds( \
    (const __attribute__((address_space(1))) unsigned int*)(gp), \
    (__attribute__((address_space(3))) unsigned int*)(lp), 16, 0, 0)

__device__ __forceinline__ float bf2f(u16 u) {
    union { unsigned int i; float f; } c; c.i = ((unsigned int)u) << 16; return c.f;
}
__device__ __forceinline__ u16 f2bf(float f) {
    union { float f; unsigned int i; } c; c.f = f;
    unsigned int r = (c.i + 0x7FFFu + ((c.i >> 16) & 1u)) >> 16;
    return (u16)r;
}
__device__ __forceinline__ void cp16(u16* dst, const u16* src) {
    *reinterpret_cast<uint4*>(dst) = *reinterpret_cast<const uint4*>(src);
}
__device__ __forceinline__ float load_in(const u16* p, size_t idx, int f32) {
    return f32 ? reinterpret_cast<const float*>(p)[idx] : bf2f(p[idx]);
}
// tiled layout index with 16B-slot XOR swizzle baked in:
// T[(row/128)*KB + col/32][row%128][slot^row & 3][col%8], KB = K/32.
__device__ __forceinline__ size_t tidx(int row, int col, int KB) {
    int c = (col & 7) | ((((col >> 3) ^ row) & 3) << 3);
    return ((size_t)((row >> 7) * KB + (col >> 5)) * 128 + (row & 127)) * 32 + c;
}

// one-time dtype sniff, hoisted: writes flag to ws
__global__ void detect_kernel(const u16* __restrict__ x, u16* __restrict__ fl) {
    if (threadIdx.x == 0) {
        int f = 0;
        for (int i = 0; i < 128; ++i) {
            float v = fabsf(bf2f(x[i]));
            if (!(v <= 1.0e3f)) f = 1;
        }
        fl[0] = (u16)f;
    }
}

// ---------------- weight prep ----------------
__global__ __launch_bounds__(256) void transpose_tiled_kernel(
        const u16* __restrict__ X, u16* __restrict__ Xt, int KB,
        const u16* __restrict__ fl) {
    __shared__ __align__(16) u16 Ts[64 * 72];
    int f32 = fl[0];
    int bi = blockIdx.y, bj = blockIdx.x;   // bi: k-tile, bj: n-tile
    int NS = gridDim.x * 64;
    int t = threadIdx.x;
    for (int p = 0; p < 2; ++p) {
        int idx = p * 256 + t;
        int row = idx >> 3, col8 = (idx & 7) * 8;
        size_t src = (size_t)(bi * 64 + row) * NS + bj * 64 + col8;
        if (f32) {
            for (int jj = 0; jj < 8; ++jj)
                Ts[row * 72 + col8 + jj] = f2bf(reinterpret_cast<const float*>(X)[src + jj]);
        } else {
            cp16(&Ts[row * 72 + col8], &X[src]);
        }
    }
    __syncthreads();
    for (int p = 0; p < 2; ++p) {
        int idx = p * 256 + t;
        int row = idx >> 3, col8 = (idx & 7) * 8;
        union { u16 u[8]; uint4 v; } tmp;
        for (int jj = 0; jj < 8; ++jj) tmp.u[jj] = Ts[(col8 + jj) * 72 + row];
        int n = bj * 64 + row, k0 = bi * 64 + col8;
        *reinterpret_cast<uint4*>(&Xt[tidx(n, k0, KB)]) = tmp.v;
    }
}

// vectorized: each thread packs 8 consecutive d (k-dim) for one (sel,hh,e)
// -> one contiguous 16B store into the tiled layout. 1536 blocks.
__global__ __launch_bounds__(256) void pack_qkv_kernel(
        const u16* __restrict__ Wq, const u16* __restrict__ Wk,
        const u16* __restrict__ Wv, u16* __restrict__ Wt,
        const u16* __restrict__ fl) {
    int f32 = fl[0];
    int idx = blockIdx.x * 256 + threadIdx.x;   // 3*16*128*64
    int e = idx & 63, d8 = (idx >> 6) & 127, hh = (idx >> 13) & 15, sel = idx >> 17;
    const u16* W = (sel == 0) ? Wq : ((sel == 1) ? Wk : Wv);
    int n = sel * 1024 + hh * 64 + e;
    size_t src = (size_t)hh * (D_EMB * HDIM) + (size_t)(d8 * 8) * HDIM + e;
    union { u16 u[8]; uint4 v; } tmp;
    for (int dd = 0; dd < 8; ++dd) {
        float v = f32 ? reinterpret_cast<const float*>(W)[src + (size_t)dd * HDIM]
                      : bf2f(W[src + (size_t)dd * HDIM]);
        tmp.u[dd] = f2bf(v);
    }
    *reinterpret_cast<uint4*>(&Wt[tidx(n, d8 * 8, 32)]) = tmp.v;
}

// ---------------- layernorm: raw-dtype input -> tiled bf16 (KB=32) ----------------
__global__ __launch_bounds__(256) void ln_kernel(
        const u16* __restrict__ X, const u16* __restrict__ g,
        const u16* __restrict__ be, u16* __restrict__ Ht,
        const u16* __restrict__ fl) {
    int f32 = fl[0];
    int row = blockIdx.x;
    int t = threadIdx.x;
    float v[4];
    float s = 0.f, sq = 0.f;
    for (int i = 0; i < 4; ++i) {
        v[i] = load_in(X, (size_t)row * D_EMB + t + i * 256, f32);
        s += v[i]; sq += v[i] * v[i];
    }
    for (int m = 32; m; m >>= 1) { s += __shfl_down(s, m); sq += __shfl_down(sq, m); }
    __shared__ float red[8];
    int wid = t >> 6, lane = t & 63;
    if (lane == 0) { red[wid] = s; red[wid + 4] = sq; }
    __syncthreads();
    if (t == 0) {
        float S = red[0] + red[1] + red[2] + red[3];
        float SQ = red[4] + red[5] + red[6] + red[7];
        float mean = S * (1.f / 1024.f);
        float var = SQ * (1.f / 1024.f) - mean * mean;
        red[0] = mean; red[1] = rsqrtf(var + 1e-5f);
    }
    __syncthreads();
    float mean = red[0], rstd = red[1];
    for (int i = 0; i < 4; ++i) {
        int c = t + i * 256;
        float hv = (v[i] - mean) * rstd * load_in(g, c, f32) + load_in(be, c, f32);
        Ht[tidx(row, c, 32)] = f2bf(hv);
    }
}

// ---------------- GEMM: async 2-phase K-loop (global_load_lds dbuf, 1 barrier) ---
// flags: 1=relu, 2=out_ext, 4=c_tiled, 8=qkv-split
template<int TAG, int TN>
__global__ __launch_bounds__(256) void gemm_t(
        const u16* __restrict__ At, const u16* __restrict__ Bt, u16* __restrict__ C,
        u16* __restrict__ C2,
        const u16* __restrict__ bias, const u16* __restrict__ res,
        int N, int K, int flags, int row_off,
        const u16* __restrict__ fl) {
    constexpr int NF = (TN == 128) ? 4 : 2;       // 16-wide n-frags per wave
    __shared__ __align__(16) u16 As2[2][4096];
    __shared__ __align__(16) u16 Bs2[2][TN * 32];
    int f32 = fl[0];
    int t = threadIdx.x;
    int gx = gridDim.x, gy = gridDim.y;
    int id = blockIdx.y * gx + blockIdx.x;
    int total = gx * gy;
    // XCD swizzle: xcd=id&7 owns 4-wide x th-tall block tiles
    int xcd = id & 7, seq = id >> 3, P = total >> 3;
    int tpb = (P >= 32) ? 32 : 16;
    int th  = (P >= 32) ? 8 : 4;
    int tile = xcd * (P / tpb) + seq / tpb;
    int within = seq % tpb;
    int tiles_x = gx >> 2;
    int bx = (tile % tiles_x) * 4 + (within & 3);
    int by = (tile / tiles_x) * th + (within >> 2);
    int n0 = bx * TN, m0 = by * 128;
    int w = t >> 6, lane = t & 63, quad = lane >> 4, l16 = lane & 15;
    int wm = (TN == 128) ? (w >> 1) * 64 : (w & 1) * 64;
    int wn = (TN == 128) ? (w & 1) * 64  : (w >> 1) * 32;
    int KB = K >> 5;
    int kb0 = (seq * (KB >> 5)) & (KB - 1);       // stagger start (KB pow2)
    const u16* Ab = At + (size_t)(m0 >> 7) * KB * 4096 + w * 512 + lane * 8;
    const u16* Bb = Bt + (size_t)(n0 >> 7) * KB * 4096
                       + ((TN == 64) ? (n0 & 64) * 32 : 0) + w * 512 + lane * 8;

    auto stage = [&](int buf, int kb) {
        const u16* ga = Ab + (size_t)kb * 4096;
        const u16* gb = Bb + (size_t)kb * 4096;
        u16* la = &As2[buf][w * 512];
        u16* lb = &Bs2[buf][w * 512];
        GLD16(la, ga);
        GLD16(la + 2048, ga + 2048);
        GLD16(lb, gb);
        if constexpr (TN == 128) { GLD16(lb + 2048, gb + 2048); }
    };

    const f32x4 fz = {0.f, 0.f, 0.f, 0.f};
    f32x4 acc[4][NF];
    for (int mt = 0; mt < 4; ++mt)
        for (int nt = 0; nt < NF; ++nt) acc[mt][nt] = fz;

    stage(0, kb0);
    __syncthreads();
    int kb = kb0;
    for (int it = 0; it < KB; ++it) {
        int cur = it & 1;
        int kn = (kb + 1 == KB) ? 0 : kb + 1;
        if (it + 1 < KB) stage(cur ^ 1, kn);      // async prefetch during MFMAs
        bf16x8 af[4], bfr[NF];
        for (int mt = 0; mt < 4; ++mt) {
            int r = wm + mt * 16 + l16;
            af[mt] = *reinterpret_cast<const bf16x8*>(
                &As2[cur][r * 32 + (((quad ^ r) & 3) << 3)]);
        }
        for (int nt = 0; nt < NF; ++nt) {
            int r = wn + nt * 16 + l16;
            bfr[nt] = *reinterpret_cast<const bf16x8*>(
                &Bs2[cur][r * 32 + (((quad ^ r) & 3) << 3)]);
        }
        for (int mt = 0; mt < 4; ++mt)
            for (int nt = 0; nt < NF; ++nt)
                acc[mt][nt] = __builtin_amdgcn_mfma_f32_16x16x32_bf16(af[mt], bfr[nt], acc[mt][nt], 0, 0, 0);
        __syncthreads();                          // drains prefetch (vmcnt) + reads
        kb = kn;
    }

    int relu_f = flags & 1, out_ext = flags & 2, c_tiled = flags & 4, qkvsp = flags & 8;
    if (qkvsp) {
        for (int mt = 0; mt < 4; ++mt)
            for (int nt = 0; nt < NF; ++nt) {
                int gc = n0 + wn + nt * 16 + l16;
                int grb = m0 + wm + mt * 16 + quad * 4;
                if (gc < 2048) {
                    for (int r = 0; r < 4; ++r)
                        C[(size_t)(grb + r) * 2048 + gc] = f2bf(acc[mt][nt][r]);
                } else {
                    int hh = (gc - 2048) >> 6, d = gc & 63;
                    int bb = grb >> 11, s = grb & 2047;
                    union { u16 u[4]; uint2 v; } pk;
                    for (int r = 0; r < 4; ++r) pk.u[r] = f2bf(acc[mt][nt][r]);
                    *reinterpret_cast<uint2*>(
                        &C2[(((size_t)bb * 16 + hh) * 64 + d) * 2048 + s]) = pk.v;
                }
            }
        return;
    }
    for (int mt = 0; mt < 4; ++mt)
        for (int nt = 0; nt < NF; ++nt)
            for (int r = 0; r < 4; ++r) {
                int gr = m0 + wm + mt * 16 + quad * 4 + r;
                int gc = n0 + wn + nt * 16 + l16;
                float v = acc[mt][nt][r];
                if (bias) v += load_in(bias, gc, f32);
                if (relu_f) v = v > 0.f ? v : 0.f;
                size_t oidx = (size_t)(row_off + gr) * N + gc;
                if (res) v += load_in(res, oidx, f32);
                if (c_tiled)      C[tidx(gr, gc, N >> 5)] = f2bf(v);
                else if (out_ext && f32) reinterpret_cast<float*>(C)[oidx] = v;
                else              C[oidx] = f2bf(v);
            }
}

// ---------------- split-K GEMM (atomic f32 partials) ------
template<int TAG, int KBL, int TN>
__global__ __launch_bounds__(256) void gemm_sk_t(
        const u16* __restrict__ At, const u16* __restrict__ Bt,
        float* __restrict__ Pp, int N, int K) {
    constexpr int NF = (TN == 128) ? 4 : 2;
    __shared__ __align__(16) u16 As2[2][4096];
    __shared__ __align__(16) u16 Bs2[2][TN * 32];
    int t = threadIdx.x;
    int gx = gridDim.x, gy = gridDim.y;
    int id = blockIdx.y * gx + blockIdx.x;
    int total = gx * gy;
    int xcd = id & 7, seq = id >> 3, P = total >> 3;
    int tpb = (P >= 32) ? 32 : 16;
    int th  = (P >= 32) ? 8 : 4;
    int tile = xcd * (P / tpb) + seq / tpb;
    int within = seq % tpb;
    int tiles_x = gx >> 2;
    int bx = (tile % tiles_x) * 4 + (within & 3);
    int by = (tile / tiles_x) * th + (within >> 2);
    int n0 = bx * TN, m0 = by * 128;
    int w = t >> 6, lane = t & 63, quad = lane >> 4, l16 = lane & 15;
    int wm = (TN == 128) ? (w >> 1) * 64 : (w & 1) * 64;
    int wn = (TN == 128) ? (w & 1) * 64  : (w >> 1) * 32;
    int KB = K >> 5;
    int kstart = blockIdx.z * KBL;
    int rel0 = seq & (KBL - 1);                   // stagger within z-slice
    const u16* Ab = At + (size_t)(m0 >> 7) * KB * 4096 + w * 512 + lane * 8;
    const u16* Bb = Bt + (size_t)(n0 >> 7) * KB * 4096
                       + ((TN == 64) ? (n0 & 64) * 32 : 0) + w * 512 + lane * 8;

    auto stage = [&](int buf, int kb) {
        const u16* ga = Ab + (size_t)kb * 4096;
        const u16* gb = Bb + (size_t)kb * 4096;
        u16* la = &As2[buf][w * 512];
        u16* lb = &Bs2[buf][w * 512];
        GLD16(la, ga);
        GLD16(la + 2048, ga + 2048);
        GLD16(lb, gb);
        if constexpr (TN == 128) { GLD16(lb + 2048, gb + 2048); }
    };

    const f32x4 fz = {0.f, 0.f, 0.f, 0.f};
    f32x4 acc[4][NF];
    for (int mt = 0; mt < 4; ++mt)
        for (int nt = 0; nt < NF; ++nt) acc[mt][nt] = fz;

    stage(0, kstart + rel0);
    __syncthreads();
    for (int it = 0; it < KBL; ++it) {
        int cur = it & 1;
        if (it + 1 < KBL)
            stage(cur ^ 1, kstart + ((rel0 + it + 1) & (KBL - 1)));
        bf16x8 af[4], bfr[NF];
        for (int mt = 0; mt < 4; ++mt) {
            int r = wm + mt * 16 + l16;
            af[mt] = *reinterpret_cast<const bf16x8*>(
                &As2[cur][r * 32 + (((quad ^ r) & 3) << 3)]);
        }
        for (int nt = 0; nt < NF; ++nt) {
            int r = wn + nt * 16 + l16;
            bfr[nt] = *reinterpret_cast<const bf16x8*>(
                &Bs2[cur][r * 32 + (((quad ^ r) & 3) << 3)]);
        }
        for (int mt = 0; mt < 4; ++mt)
            for (int nt = 0; nt < NF; ++nt)
                acc[mt][nt] = __builtin_amdgcn_mfma_f32_16x16x32_bf16(af[mt], bfr[nt], acc[mt][nt], 0, 0, 0);
        __syncthreads();
    }

    for (int mt = 0; mt < 4; ++mt)
        for (int nt = 0; nt < NF; ++nt)
            for (int r = 0; r < 4; ++r) {
                int gr = m0 + wm + mt * 16 + quad * 4 + r;
                int gc = n0 + wn + nt * 16 + l16;
                atomicAdd(&Pp[(size_t)gr * N + gc], acc[mt][nt][r]);
            }
}

__global__ __launch_bounds__(256) void zero_f32_kernel(float* __restrict__ p) {
    const f32x4 fz = {0.f, 0.f, 0.f, 0.f};
    reinterpret_cast<f32x4*>(p)[(size_t)blockIdx.x * 256 + threadIdx.x] = fz;
}

// finalize FFN: out[r][c] = P[r][c] + b2[c] + out(residual, already stored)
__global__ __launch_bounds__(256) void ffn_fin_kernel(
        const float* __restrict__ Pp, const u16* __restrict__ b2,
        u16* __restrict__ out, int row_off, const u16* __restrict__ fl) {
    int f32 = fl[0];
    size_t i = ((size_t)blockIdx.x * 256 + threadIdx.x) * 4;
    int col = (int)(i & 1023);
    f32x4 pv = *reinterpret_cast<const f32x4*>(Pp + i);
    size_t o = (size_t)row_off * 1024 + i;
    if (f32) {
        float* of = reinterpret_cast<float*>(out);
        f32x4 ov = *reinterpret_cast<f32x4*>(of + o);
        for (int j = 0; j < 4; ++j)
            ov[j] += pv[j] + load_in(b2, col + j, 1);
        *reinterpret_cast<f32x4*>(of + o) = ov;
    } else {
        for (int j = 0; j < 4; ++j) {
            float v = bf2f(out[o + j]) + pv[j] + bf2f(b2[col + j]);
            out[o + j] = f2bf(v);
        }
    }
}

// finalize out-proj + LN2 fused: block = one row.
// out[row][c] = P + bo + x (residual); h2t[row] = LN(out row) tiled bf16.
__global__ __launch_bounds__(256) void oproj_fin_ln2_kernel(
        const float* __restrict__ Pp, const u16* __restrict__ bo,
        const u16* __restrict__ x, const u16* __restrict__ g2,
        const u16* __restrict__ be2, u16* __restrict__ out,
        u16* __restrict__ h2t, const u16* __restrict__ fl) {
    int f32 = fl[0];
    int row = blockIdx.x;
    int t = threadIdx.x;
    size_t base = (size_t)row * 1024 + t * 4;
    f32x4 pv = *reinterpret_cast<const f32x4*>(Pp + base);
    float v[4];
    float s = 0.f, sq = 0.f;
    for (int j = 0; j < 4; ++j) {
        v[j] = load_in(x, base + j, f32) + pv[j] + load_in(bo, t * 4 + j, f32);
        s += v[j]; sq += v[j] * v[j];
    }
    if (f32) {
        f32x4 ov = {v[0], v[1], v[2], v[3]};
        *reinterpret_cast<f32x4*>(reinterpret_cast<float*>(out) + base) = ov;
    } else {
        union { u16 u[4]; uint2 q; } pk;
        for (int j = 0; j < 4; ++j) pk.u[j] = f2bf(v[j]);
        *reinterpret_cast<uint2*>(&out[base]) = pk.q;
    }
    for (int m = 32; m; m >>= 1) { s += __shfl_down(s, m); sq += __shfl_down(sq, m); }
    __shared__ float red[8];
    int wid = t >> 6, lane = t & 63;
    if (lane == 0) { red[wid] = s; red[wid + 4] = sq; }
    __syncthreads();
    if (t == 0) {
        float S = red[0] + red[1] + red[2] + red[3];
        float SQ = red[4] + red[5] + red[6] + red[7];
        float mean = S * (1.f / 1024.f);
        float var = SQ * (1.f / 1024.f) - mean * mean;
        red[0] = mean; red[1] = rsqrtf(var + 1e-5f);
    }
    __syncthreads();
    float mean = red[0], rstd = red[1];
    for (int j = 0; j < 4; ++j) {
        int c = t * 4 + j;
        float hv = (v[j] - mean) * rstd * load_in(g2, c, f32) + load_in(be2, c, f32);
        h2t[tidx(row, c, 32)] = f2bf(hv);
    }
}

// ---------------- flash attention (R9 version: pair-balanced, barrier-free) ----
// qk: [4096][2048] rowmajor (Q cols 0..1023, K cols 1024..2047)
// vt: [b*16+h][64 d][2048 s] planes (V transposed, by QKV gemm)
// Block = 128 thr (2 waves) owning 32 Q-rows; processes column pair
// (tq=31-px heavy, then tq=px light) -> every block runs exactly 33 j-iters.
__global__ __launch_bounds__(128) void flash_kernel(
        const u16* __restrict__ qk, const u16* __restrict__ vt,
        u16* __restrict__ attn_t) {
    __shared__ __align__(16) u16 Ps[32 * 72];
    int t = threadIdx.x;
    int px = blockIdx.x & 15, rh = blockIdx.x >> 4;
    int b = blockIdx.y >> 4, h = blockIdx.y & 15;
    int wid = t >> 6, lane = t & 63, quad = lane >> 4, l16 = lane & 15;
    int g = rh * 2 + wid;                         // global 16-row group 0..3
    const size_t seq_base = (size_t)b * TSEQ;
    const u16* vplane = vt + (size_t)(b * 16 + h) * 64 * 2048;

    for (int half = 0; half < 2; ++half) {
        int tq = half ? px : (31 - px);

        bf16x8 aq[2];
        for (int kit = 0; kit < 2; ++kit)
            aq[kit] = *reinterpret_cast<const bf16x8*>(
                &qk[(seq_base + tq * 64 + g * 16 + l16) * 2048 + h * 64 + kit * 32 + quad * 8]);

        const f32x4 fz = {0.f, 0.f, 0.f, 0.f};
        float m_run[4], l_run[4];
        f32x4 o[4];
        for (int r = 0; r < 4; ++r) { m_run[r] = NEG_BIG; l_run[r] = 0.f; }
        for (int nt = 0; nt < 4; ++nt) o[nt] = fz;

        for (int j = 0; j <= tq; ++j) {
            f32x4 sa[4];
            for (int nt = 0; nt < 4; ++nt) sa[nt] = fz;
            for (int kit = 0; kit < 2; ++kit) {
                for (int nt = 0; nt < 4; ++nt) {
                    bf16x8 bk = *reinterpret_cast<const bf16x8*>(
                        &qk[(seq_base + j * 64 + nt * 16 + l16) * 2048 + 1024 + h * 64 + kit * 32 + quad * 8]);
                    sa[nt] = __builtin_amdgcn_mfma_f32_16x16x32_bf16(aq[kit], bk, sa[nt], 0, 0, 0);
                }
            }

            float p_val[4][4];
            int qbase = tq * 64 + g * 16 + quad * 4;
            int sbase = j * 64 + l16;
            for (int r = 0; r < 4; ++r) {
                float sv[4];
                float mx = NEG_BIG;
                for (int nt = 0; nt < 4; ++nt) {
                    float xv = sa[nt][r] * 0.03125f;   // D^-0.5 = 1/32
                    if (sbase + nt * 16 > qbase + r) xv = NEG_BIG;
                    sv[nt] = xv;
                    mx = fmaxf(mx, xv);
                }
                for (int m = 1; m < 16; m <<= 1) mx = fmaxf(mx, __shfl_xor(mx, m));
                float mnew = fmaxf(m_run[r], mx);
                float alpha = __expf(m_run[r] - mnew);
                m_run[r] = mnew;
                float rs = 0.f;
                for (int nt = 0; nt < 4; ++nt) {
                    float pv = __expf(sv[nt] - mnew);
                    p_val[nt][r] = pv;
                    rs += pv;
                }
                for (int m = 1; m < 16; m <<= 1) rs += __shfl_xor(rs, m);
                l_run[r] = l_run[r] * alpha + rs;
                for (int nt = 0; nt < 4; ++nt) o[nt][r] *= alpha;
            }

            // wave-private Ps stripe: same-wave LDS ordering, no barrier needed
            for (int nt = 0; nt < 4; ++nt)
                for (int r = 0; r < 4; ++r)
                    Ps[(wid * 16 + quad * 4 + r) * 72 + nt * 16 + l16] = f2bf(p_val[nt][r]);

            for (int kit = 0; kit < 2; ++kit) {
                bf16x8 ap = *reinterpret_cast<const bf16x8*>(
                    &Ps[(wid * 16 + l16) * 72 + kit * 32 + quad * 8]);
                for (int nt = 0; nt < 4; ++nt) {
                    bf16x8 bv = *reinterpret_cast<const bf16x8*>(
                        &vplane[(size_t)(nt * 16 + l16) * 2048 + j * 64 + kit * 32 + quad * 8]);
                    o[nt] = __builtin_amdgcn_mfma_f32_16x16x32_bf16(ap, bv, o[nt], 0, 0, 0);
                }
            }
        }

        for (int nt = 0; nt < 4; ++nt)
            for (int r = 0; r < 4; ++r) {
                int trow = (int)seq_base + tq * 64 + g * 16 + quad * 4 + r;
                int col = h * 64 + nt * 16 + l16;
                attn_t[tidx(trow, col, 32)] = f2bf(o[nt][r] / l_run[r]);
            }
    }
}

// ---------------- launch ----------------
// sk layout (ws elems, 1M=1<<20; needs >= 58MB = 29M elems):
//  [ 0, 8M): qk rowmajor -> Pp_oproj (4M f32) -> a1 [0,16M) (FFN, tiled [4096][4096])
//  [ 8,12M): vt planes -> a1 part
//  [12,16M): attn_t (tiled) -> a1 part
//  [16,20M): W1t -> Pp_ffn part ([16,24M) as 4M f32)
//  [20,24M): h (LN1) -> Wot [20,21M) -> h2 (LN2 out) -> Pp_ffn part
//  [24,27M): Wtq -> W2t [24,28M)
//  [28M]:    dtype flag
extern "C" void kernel_launch(void* const* d_in, const int* in_sizes, int n_in,
                              void* d_out, int out_size, void* d_ws, size_t ws_size,
                              hipStream_t stream) {
    const u16* x   = (const u16*)d_in[0];
    const u16* Wq  = (const u16*)d_in[1];
    const u16* Wk  = (const u16*)d_in[2];
    const u16* Wv  = (const u16*)d_in[3];
    const u16* Wo  = (const u16*)d_in[4];
    const u16* bo  = (const u16*)d_in[5];
    const u16* W1  = (const u16*)d_in[6];
    const u16* b1  = (const u16*)d_in[7];
    const u16* W2  = (const u16*)d_in[8];
    const u16* b2  = (const u16*)d_in[9];
    const u16* g1  = (const u16*)d_in[10];
    const u16* be1 = (const u16*)d_in[11];
    const u16* g2  = (const u16*)d_in[12];
    const u16* be2 = (const u16*)d_in[13];
    u16* out = (u16*)d_out;

    const size_t M1 = (size_t)1 << 20;
    u16* ws = (u16*)d_ws;
    bool sk = ws_size >= ((size_t)58 << 20);

    if (sk) {
        u16* qk   = ws;                 // [0,8M)
        u16* vt   = ws + 8 * M1;        // [8,12M)
        u16* attn = ws + 12 * M1;       // [12,16M)
        u16* W1t  = ws + 16 * M1;       // [16,20M)
        u16* h    = ws + 20 * M1;       // [20,24M) LN1 out
        u16* Wot  = ws + 20 * M1;       // [20,21M) after gemm0
        u16* h2   = ws + 20 * M1;       // [20,24M) LN2 out (after oproj)
        u16* Wtq  = ws + 24 * M1;       // [24,27M)
        u16* W2t  = ws + 24 * M1;       // [24,28M) after gemm0
        u16* a1   = ws;                 // [0,16M) after oproj
        float* PpO = reinterpret_cast<float*>(ws);            // [0,8M) as 4M f32
        float* PpF = reinterpret_cast<float*>(ws + 16 * M1);  // [16,24M) as 4M f32
        u16* fl   = ws + 28 * M1;

        detect_kernel<<<1, 64, 0, stream>>>(x, fl);

        // LN1 + QKV projection (Q,K rowmajor; V -> vt transposed planes)
        pack_qkv_kernel<<<1536, 256, 0, stream>>>(Wq, Wk, Wv, Wtq, fl);
        ln_kernel<<<NTOK, 256, 0, stream>>>(x, g1, be1, h, fl);
        gemm_t<0, 64><<<dim3(48, 32), 256, 0, stream>>>(
            h, Wtq, qk, vt, nullptr, nullptr, 3072, 1024, 8, 0, fl);

        // Wo repack (h dead)
        transpose_tiled_kernel<<<dim3(16, 16), 256, 0, stream>>>(Wo, Wot, 32, fl);

        // attention (pair-balanced R9 kernel)
        flash_kernel<<<dim3(32, 32), 128, 0, stream>>>(qk, vt, attn);

        // out-proj split-K (qk dead -> PpO) + fused fin+LN2
        zero_f32_kernel<<<4096, 256, 0, stream>>>(PpO);
        gemm_sk_t<2, 8, 64><<<dim3(16, 32, 4), 256, 0, stream>>>(attn, Wot, PpO, 1024, 1024);
        oproj_fin_ln2_kernel<<<4096, 256, 0, stream>>>(PpO, bo, x, g2, be2, out, h2, fl);

        // weight repacks (Wtq dead -> W2t; [16,20M) free -> W1t)
        transpose_tiled_kernel<<<dim3(16, 64), 256, 0, stream>>>(W2, W2t, 128, fl);
        transpose_tiled_kernel<<<dim3(64, 16), 256, 0, stream>>>(W1, W1t, 32, fl);

        // FFN up: single M=4096 dispatch, 2048 blocks (PpO/attn dead -> a1)
        gemm_t<2, 64><<<dim3(64, 32), 256, 0, stream>>>(
            h2, W1t, a1, nullptr, b1, nullptr, 4096, 1024, 1 | 4, 0, fl);
        // FFN down: single M=4096 split-K chain (W1t/h2 dead -> PpF)
        zero_f32_kernel<<<4096, 256, 0, stream>>>(PpF);
        gemm_sk_t<0, 32, 64><<<dim3(16, 32, 4), 256, 0, stream>>>(a1, W2t, PpF, 1024, 4096);
        ffn_fin_kernel<<<4096, 256, 0, stream>>>(PpF, b2, out, 0, fl);
    } else {
        // fallback (<58MB): chunked non-sk path, 40MB layout
        u16* qk   = ws;                 // [0,8M)
        u16* vt   = ws + 8 * M1;        // [8,12M)
        u16* h    = ws + 12 * M1;       // [12,16M)
        u16* attn = ws + 12 * M1;
        u16* h2   = ws + 12 * M1;
        u16* Wtq  = ws + 16 * M1;       // [16,19M)
        u16* Wot  = ws + 16 * M1;
        u16* W1t  = ws + 16 * M1;       // [16,20M)
        u16* W2t  = ws;                 // [0,4M) after flash
        u16* a1   = ws + 4 * M1;        // [4,12M) per 2048-row chunk
        u16* fl   = ws + 20 * M1;

        detect_kernel<<<1, 64, 0, stream>>>(x, fl);
        pack_qkv_kernel<<<1536, 256, 0, stream>>>(Wq, Wk, Wv, Wtq, fl);
        ln_kernel<<<NTOK, 256, 0, stream>>>(x, g1, be1, h, fl);
        gemm_t<0, 64><<<dim3(48, 32), 256, 0, stream>>>(
            h, Wtq, qk, vt, nullptr, nullptr, 3072, 1024, 8, 0, fl);
        transpose_tiled_kernel<<<dim3(16, 16), 256, 0, stream>>>(Wo, Wot, 32, fl);
        flash_kernel<<<dim3(32, 32), 128, 0, stream>>>(qk, vt, attn);
        gemm_t<1, 128><<<dim3(8, 32), 256, 0, stream>>>(
            attn, Wot, out, nullptr, bo, x, 1024, 1024, 2, 0, fl);
        transpose_tiled_kernel<<<dim3(16, 64), 256, 0, stream>>>(W2, W2t, 128, fl);
        transpose_tiled_kernel<<<dim3(64, 16), 256, 0, stream>>>(W1, W1t, 32, fl);
        ln_kernel<<<NTOK, 256, 0, stream>>>(out, g2, be2, h2, fl);
        gemm_t<2, 64><<<dim3(64, 16), 256, 0, stream>>>(
            h2, W1t, a1, nullptr, b1, nullptr, 4096, 1024, 1 | 4, 0, fl);
        gemm_t<4, 128><<<dim3(8, 16), 256, 0, stream>>>(
            a1, W2t, out, nullptr, b2, out, 1024, 4096, 2, 0, fl);
        gemm_t<3, 64><<<dim3(64, 16), 256, 0, stream>>>(
            h2 + (size_t)2 * M1, W1t, a1, nullptr, b1, nullptr, 4096, 1024, 1 | 4, 0, fl);
        gemm_t<5, 128><<<dim3(8, 16), 256, 0, stream>>>(
            a1, W2t, out, nullptr, b2, out, 1024, 4096, 2, 2048, fl);
    }
}

// Round 12
// 555.553 us; speedup vs baseline: 1.1592x; 1.1057x over previous
//
#include <hip/hip_runtime.h>
#include <stdint.h>

typedef unsigned short u16;
typedef __attribute__((ext_vector_type(8))) __bf16 bf16x8;
typedef __attribute__((ext_vector_type(4))) float f32x4;

#define D_EMB 1024
#define NHEAD 16
#define HDIM 64
#define TSEQ 2048
#define NTOK 4096
#define NEG_BIG -1.0e30f

// async global->LDS, 16B per lane; LDS dest = wave-uniform base + lane*16
#define GLD16(lp, gp) __builtin_amdgcn_global_load_lds( \
    (const __attribute__((address_space(1))) unsigned int*)(gp), \
    (__attribute__((address_space(3))) unsigned int*)(lp), 16, 0, 0)

__device__ __forceinline__ float bf2f(u16 u) {
    union { unsigned int i; float f; } c; c.i = ((unsigned int)u) << 16; return c.f;
}
__device__ __forceinline__ u16 f2bf(float f) {
    union { float f; unsigned int i; } c; c.f = f;
    unsigned int r = (c.i + 0x7FFFu + ((c.i >> 16) & 1u)) >> 16;
    return (u16)r;
}
__device__ __forceinline__ void cp16(u16* dst, const u16* src) {
    *reinterpret_cast<uint4*>(dst) = *reinterpret_cast<const uint4*>(src);
}
__device__ __forceinline__ float load_in(const u16* p, size_t idx, int f32) {
    return f32 ? reinterpret_cast<const float*>(p)[idx] : bf2f(p[idx]);
}
// tiled layout index with 16B-slot XOR swizzle baked in:
// T[(row/128)*KB + col/32][row%128][slot^row & 3][col%8], KB = K/32.
__device__ __forceinline__ size_t tidx(int row, int col, int KB) {
    int c = (col & 7) | ((((col >> 3) ^ row) & 3) << 3);
    return ((size_t)((row >> 7) * KB + (col >> 5)) * 128 + (row & 127)) * 32 + c;
}

// one-time dtype sniff, hoisted: writes flag to ws
__global__ void detect_kernel(const u16* __restrict__ x, u16* __restrict__ fl) {
    if (threadIdx.x == 0) {
        int f = 0;
        for (int i = 0; i < 128; ++i) {
            float v = fabsf(bf2f(x[i]));
            if (!(v <= 1.0e3f)) f = 1;
        }
        fl[0] = (u16)f;
    }
}

// ---------------- weight prep ----------------
__global__ __launch_bounds__(256) void transpose_tiled_kernel(
        const u16* __restrict__ X, u16* __restrict__ Xt, int KB,
        const u16* __restrict__ fl) {
    __shared__ __align__(16) u16 Ts[64 * 72];
    int f32 = fl[0];
    int bi = blockIdx.y, bj = blockIdx.x;   // bi: k-tile, bj: n-tile
    int NS = gridDim.x * 64;
    int t = threadIdx.x;
    for (int p = 0; p < 2; ++p) {
        int idx = p * 256 + t;
        int row = idx >> 3, col8 = (idx & 7) * 8;
        size_t src = (size_t)(bi * 64 + row) * NS + bj * 64 + col8;
        if (f32) {
            for (int jj = 0; jj < 8; ++jj)
                Ts[row * 72 + col8 + jj] = f2bf(reinterpret_cast<const float*>(X)[src + jj]);
        } else {
            cp16(&Ts[row * 72 + col8], &X[src]);
        }
    }
    __syncthreads();
    for (int p = 0; p < 2; ++p) {
        int idx = p * 256 + t;
        int row = idx >> 3, col8 = (idx & 7) * 8;
        union { u16 u[8]; uint4 v; } tmp;
        for (int jj = 0; jj < 8; ++jj) tmp.u[jj] = Ts[(col8 + jj) * 72 + row];
        int n = bj * 64 + row, k0 = bi * 64 + col8;
        *reinterpret_cast<uint4*>(&Xt[tidx(n, k0, KB)]) = tmp.v;
    }
}

// vectorized: each thread packs 8 consecutive d (k-dim) for one (sel,hh,e)
__global__ __launch_bounds__(256) void pack_qkv_kernel(
        const u16* __restrict__ Wq, const u16* __restrict__ Wk,
        const u16* __restrict__ Wv, u16* __restrict__ Wt,
        const u16* __restrict__ fl) {
    int f32 = fl[0];
    int idx = blockIdx.x * 256 + threadIdx.x;   // 3*16*128*64
    int e = idx & 63, d8 = (idx >> 6) & 127, hh = (idx >> 13) & 15, sel = idx >> 17;
    const u16* W = (sel == 0) ? Wq : ((sel == 1) ? Wk : Wv);
    int n = sel * 1024 + hh * 64 + e;
    size_t src = (size_t)hh * (D_EMB * HDIM) + (size_t)(d8 * 8) * HDIM + e;
    union { u16 u[8]; uint4 v; } tmp;
    for (int dd = 0; dd < 8; ++dd) {
        float v = f32 ? reinterpret_cast<const float*>(W)[src + (size_t)dd * HDIM]
                      : bf2f(W[src + (size_t)dd * HDIM]);
        tmp.u[dd] = f2bf(v);
    }
    *reinterpret_cast<uint4*>(&Wt[tidx(n, d8 * 8, 32)]) = tmp.v;
}

// ---------------- layernorm: raw-dtype input -> tiled bf16 (KB=32) ----------------
__global__ __launch_bounds__(256) void ln_kernel(
        const u16* __restrict__ X, const u16* __restrict__ g,
        const u16* __restrict__ be, u16* __restrict__ Ht,
        const u16* __restrict__ fl) {
    int f32 = fl[0];
    int row = blockIdx.x;
    int t = threadIdx.x;
    float v[4];
    float s = 0.f, sq = 0.f;
    for (int i = 0; i < 4; ++i) {
        v[i] = load_in(X, (size_t)row * D_EMB + t + i * 256, f32);
        s += v[i]; sq += v[i] * v[i];
    }
    for (int m = 32; m; m >>= 1) { s += __shfl_down(s, m); sq += __shfl_down(sq, m); }
    __shared__ float red[8];
    int wid = t >> 6, lane = t & 63;
    if (lane == 0) { red[wid] = s; red[wid + 4] = sq; }
    __syncthreads();
    if (t == 0) {
        float S = red[0] + red[1] + red[2] + red[3];
        float SQ = red[4] + red[5] + red[6] + red[7];
        float mean = S * (1.f / 1024.f);
        float var = SQ * (1.f / 1024.f) - mean * mean;
        red[0] = mean; red[1] = rsqrtf(var + 1e-5f);
    }
    __syncthreads();
    float mean = red[0], rstd = red[1];
    for (int i = 0; i < 4; ++i) {
        int c = t + i * 256;
        float hv = (v[i] - mean) * rstd * load_in(g, c, f32) + load_in(be, c, f32);
        Ht[tidx(row, c, 32)] = f2bf(hv);
    }
}

// ---------------- GEMM: async 2-phase K-loop (global_load_lds dbuf, 1 barrier) ---
// flags: 1=relu, 2=out_ext, 4=c_tiled, 8=qkv-split
template<int TAG, int TN>
__global__ __launch_bounds__(256) void gemm_t(
        const u16* __restrict__ At, const u16* __restrict__ Bt, u16* __restrict__ C,
        u16* __restrict__ C2,
        const u16* __restrict__ bias, const u16* __restrict__ res,
        int N, int K, int flags, int row_off,
        const u16* __restrict__ fl) {
    constexpr int NF = (TN == 128) ? 4 : 2;       // 16-wide n-frags per wave
    __shared__ __align__(16) u16 As2[2][4096];
    __shared__ __align__(16) u16 Bs2[2][TN * 32];
    int f32 = fl[0];
    int t = threadIdx.x;
    int gx = gridDim.x, gy = gridDim.y;
    int id = blockIdx.y * gx + blockIdx.x;
    int total = gx * gy;
    // XCD swizzle: xcd=id&7 owns 4-wide x th-tall block tiles
    int xcd = id & 7, seq = id >> 3, P = total >> 3;
    int tpb = (P >= 32) ? 32 : 16;
    int th  = (P >= 32) ? 8 : 4;
    int tile = xcd * (P / tpb) + seq / tpb;
    int within = seq % tpb;
    int tiles_x = gx >> 2;
    int bx = (tile % tiles_x) * 4 + (within & 3);
    int by = (tile / tiles_x) * th + (within >> 2);
    int n0 = bx * TN, m0 = by * 128;
    int w = t >> 6, lane = t & 63, quad = lane >> 4, l16 = lane & 15;
    int wm = (TN == 128) ? (w >> 1) * 64 : (w & 1) * 64;
    int wn = (TN == 128) ? (w & 1) * 64  : (w >> 1) * 32;
    int KB = K >> 5;
    int kb0 = (seq * (KB >> 5)) & (KB - 1);       // stagger start (KB pow2)
    const u16* Ab = At + (size_t)(m0 >> 7) * KB * 4096 + w * 512 + lane * 8;
    const u16* Bb = Bt + (size_t)(n0 >> 7) * KB * 4096
                       + ((TN == 64) ? (n0 & 64) * 32 : 0) + w * 512 + lane * 8;

    auto stage = [&](int buf, int kb) {
        const u16* ga = Ab + (size_t)kb * 4096;
        const u16* gb = Bb + (size_t)kb * 4096;
        u16* la = &As2[buf][w * 512];
        u16* lb = &Bs2[buf][w * 512];
        GLD16(la, ga);
        GLD16(la + 2048, ga + 2048);
        GLD16(lb, gb);
        if constexpr (TN == 128) { GLD16(lb + 2048, gb + 2048); }
    };

    const f32x4 fz = {0.f, 0.f, 0.f, 0.f};
    f32x4 acc[4][NF];
    for (int mt = 0; mt < 4; ++mt)
        for (int nt = 0; nt < NF; ++nt) acc[mt][nt] = fz;

    stage(0, kb0);
    __syncthreads();
    int kb = kb0;
    for (int it = 0; it < KB; ++it) {
        int cur = it & 1;
        int kn = (kb + 1 == KB) ? 0 : kb + 1;
        if (it + 1 < KB) stage(cur ^ 1, kn);      // async prefetch during MFMAs
        bf16x8 af[4], bfr[NF];
        for (int mt = 0; mt < 4; ++mt) {
            int r = wm + mt * 16 + l16;
            af[mt] = *reinterpret_cast<const bf16x8*>(
                &As2[cur][r * 32 + (((quad ^ r) & 3) << 3)]);
        }
        for (int nt = 0; nt < NF; ++nt) {
            int r = wn + nt * 16 + l16;
            bfr[nt] = *reinterpret_cast<const bf16x8*>(
                &Bs2[cur][r * 32 + (((quad ^ r) & 3) << 3)]);
        }
        for (int mt = 0; mt < 4; ++mt)
            for (int nt = 0; nt < NF; ++nt)
                acc[mt][nt] = __builtin_amdgcn_mfma_f32_16x16x32_bf16(af[mt], bfr[nt], acc[mt][nt], 0, 0, 0);
        __syncthreads();                          // drains prefetch (vmcnt) + reads
        kb = kn;
    }

    int relu_f = flags & 1, out_ext = flags & 2, c_tiled = flags & 4, qkvsp = flags & 8;
    if (qkvsp) {
        for (int mt = 0; mt < 4; ++mt)
            for (int nt = 0; nt < NF; ++nt) {
                int gc = n0 + wn + nt * 16 + l16;
                int grb = m0 + wm + mt * 16 + quad * 4;
                if (gc < 2048) {
                    for (int r = 0; r < 4; ++r)
                        C[(size_t)(grb + r) * 2048 + gc] = f2bf(acc[mt][nt][r]);
                } else {
                    int hh = (gc - 2048) >> 6, d = gc & 63;
                    int bb = grb >> 11, s = grb & 2047;
                    union { u16 u[4]; uint2 v; } pk;
                    for (int r = 0; r < 4; ++r) pk.u[r] = f2bf(acc[mt][nt][r]);
                    *reinterpret_cast<uint2*>(
                        &C2[(((size_t)bb * 16 + hh) * 64 + d) * 2048 + s]) = pk.v;
                }
            }
        return;
    }
    for (int mt = 0; mt < 4; ++mt)
        for (int nt = 0; nt < NF; ++nt)
            for (int r = 0; r < 4; ++r) {
                int gr = m0 + wm + mt * 16 + quad * 4 + r;
                int gc = n0 + wn + nt * 16 + l16;
                float v = acc[mt][nt][r];
                if (bias) v += load_in(bias, gc, f32);
                if (relu_f) v = v > 0.f ? v : 0.f;
                size_t oidx = (size_t)(row_off + gr) * N + gc;
                if (res) v += load_in(res, oidx, f32);
                if (c_tiled)      C[tidx(gr, gc, N >> 5)] = f2bf(v);
                else if (out_ext && f32) reinterpret_cast<float*>(C)[oidx] = v;
                else              C[oidx] = f2bf(v);
            }
}

// ---------------- split-K GEMM (atomic f32 partials) ------
template<int TAG, int KBL, int TN>
__global__ __launch_bounds__(256) void gemm_sk_t(
        const u16* __restrict__ At, const u16* __restrict__ Bt,
        float* __restrict__ Pp, int N, int K) {
    constexpr int NF = (TN == 128) ? 4 : 2;
    __shared__ __align__(16) u16 As2[2][4096];
    __shared__ __align__(16) u16 Bs2[2][TN * 32];
    int t = threadIdx.x;
    int gx = gridDim.x, gy = gridDim.y;
    int id = blockIdx.y * gx + blockIdx.x;
    int total = gx * gy;
    int xcd = id & 7, seq = id >> 3, P = total >> 3;
    int tpb = (P >= 32) ? 32 : 16;
    int th  = (P >= 32) ? 8 : 4;
    int tile = xcd * (P / tpb) + seq / tpb;
    int within = seq % tpb;
    int tiles_x = gx >> 2;
    int bx = (tile % tiles_x) * 4 + (within & 3);
    int by = (tile / tiles_x) * th + (within >> 2);
    int n0 = bx * TN, m0 = by * 128;
    int w = t >> 6, lane = t & 63, quad = lane >> 4, l16 = lane & 15;
    int wm = (TN == 128) ? (w >> 1) * 64 : (w & 1) * 64;
    int wn = (TN == 128) ? (w & 1) * 64  : (w >> 1) * 32;
    int KB = K >> 5;
    int kstart = blockIdx.z * KBL;
    int rel0 = seq & (KBL - 1);                   // stagger within z-slice
    const u16* Ab = At + (size_t)(m0 >> 7) * KB * 4096 + w * 512 + lane * 8;
    const u16* Bb = Bt + (size_t)(n0 >> 7) * KB * 4096
                       + ((TN == 64) ? (n0 & 64) * 32 : 0) + w * 512 + lane * 8;

    auto stage = [&](int buf, int kb) {
        const u16* ga = Ab + (size_t)kb * 4096;
        const u16* gb = Bb + (size_t)kb * 4096;
        u16* la = &As2[buf][w * 512];
        u16* lb = &Bs2[buf][w * 512];
        GLD16(la, ga);
        GLD16(la + 2048, ga + 2048);
        GLD16(lb, gb);
        if constexpr (TN == 128) { GLD16(lb + 2048, gb + 2048); }
    };

    const f32x4 fz = {0.f, 0.f, 0.f, 0.f};
    f32x4 acc[4][NF];
    for (int mt = 0; mt < 4; ++mt)
        for (int nt = 0; nt < NF; ++nt) acc[mt][nt] = fz;

    stage(0, kstart + rel0);
    __syncthreads();
    for (int it = 0; it < KBL; ++it) {
        int cur = it & 1;
        if (it + 1 < KBL)
            stage(cur ^ 1, kstart + ((rel0 + it + 1) & (KBL - 1)));
        bf16x8 af[4], bfr[NF];
        for (int mt = 0; mt < 4; ++mt) {
            int r = wm + mt * 16 + l16;
            af[mt] = *reinterpret_cast<const bf16x8*>(
                &As2[cur][r * 32 + (((quad ^ r) & 3) << 3)]);
        }
        for (int nt = 0; nt < NF; ++nt) {
            int r = wn + nt * 16 + l16;
            bfr[nt] = *reinterpret_cast<const bf16x8*>(
                &Bs2[cur][r * 32 + (((quad ^ r) & 3) << 3)]);
        }
        for (int mt = 0; mt < 4; ++mt)
            for (int nt = 0; nt < NF; ++nt)
                acc[mt][nt] = __builtin_amdgcn_mfma_f32_16x16x32_bf16(af[mt], bfr[nt], acc[mt][nt], 0, 0, 0);
        __syncthreads();
    }

    for (int mt = 0; mt < 4; ++mt)
        for (int nt = 0; nt < NF; ++nt)
            for (int r = 0; r < 4; ++r) {
                int gr = m0 + wm + mt * 16 + quad * 4 + r;
                int gc = n0 + wn + nt * 16 + l16;
                atomicAdd(&Pp[(size_t)gr * N + gc], acc[mt][nt][r]);
            }
}

__global__ __launch_bounds__(256) void zero_f32_kernel(float* __restrict__ p) {
    const f32x4 fz = {0.f, 0.f, 0.f, 0.f};
    reinterpret_cast<f32x4*>(p)[(size_t)blockIdx.x * 256 + threadIdx.x] = fz;
}

// finalize FFN: out[r][c] = P[r][c] + b2[c] + out(residual, already stored)
__global__ __launch_bounds__(256) void ffn_fin_kernel(
        const float* __restrict__ Pp, const u16* __restrict__ b2,
        u16* __restrict__ out, int row_off, const u16* __restrict__ fl) {
    int f32 = fl[0];
    size_t i = ((size_t)blockIdx.x * 256 + threadIdx.x) * 4;
    int col = (int)(i & 1023);
    f32x4 pv = *reinterpret_cast<const f32x4*>(Pp + i);
    size_t o = (size_t)row_off * 1024 + i;
    if (f32) {
        float* of = reinterpret_cast<float*>(out);
        f32x4 ov = *reinterpret_cast<f32x4*>(of + o);
        for (int j = 0; j < 4; ++j)
            ov[j] += pv[j] + load_in(b2, col + j, 1);
        *reinterpret_cast<f32x4*>(of + o) = ov;
    } else {
        for (int j = 0; j < 4; ++j) {
            float v = bf2f(out[o + j]) + pv[j] + bf2f(b2[col + j]);
            out[o + j] = f2bf(v);
        }
    }
}

// finalize out-proj + LN2 fused: block = one row.
__global__ __launch_bounds__(256) void oproj_fin_ln2_kernel(
        const float* __restrict__ Pp, const u16* __restrict__ bo,
        const u16* __restrict__ x, const u16* __restrict__ g2,
        const u16* __restrict__ be2, u16* __restrict__ out,
        u16* __restrict__ h2t, const u16* __restrict__ fl) {
    int f32 = fl[0];
    int row = blockIdx.x;
    int t = threadIdx.x;
    size_t base = (size_t)row * 1024 + t * 4;
    f32x4 pv = *reinterpret_cast<const f32x4*>(Pp + base);
    float v[4];
    float s = 0.f, sq = 0.f;
    for (int j = 0; j < 4; ++j) {
        v[j] = load_in(x, base + j, f32) + pv[j] + load_in(bo, t * 4 + j, f32);
        s += v[j]; sq += v[j] * v[j];
    }
    if (f32) {
        f32x4 ov = {v[0], v[1], v[2], v[3]};
        *reinterpret_cast<f32x4*>(reinterpret_cast<float*>(out) + base) = ov;
    } else {
        union { u16 u[4]; uint2 q; } pk;
        for (int j = 0; j < 4; ++j) pk.u[j] = f2bf(v[j]);
        *reinterpret_cast<uint2*>(&out[base]) = pk.q;
    }
    for (int m = 32; m; m >>= 1) { s += __shfl_down(s, m); sq += __shfl_down(sq, m); }
    __shared__ float red[8];
    int wid = t >> 6, lane = t & 63;
    if (lane == 0) { red[wid] = s; red[wid + 4] = sq; }
    __syncthreads();
    if (t == 0) {
        float S = red[0] + red[1] + red[2] + red[3];
        float SQ = red[4] + red[5] + red[6] + red[7];
        float mean = S * (1.f / 1024.f);
        float var = SQ * (1.f / 1024.f) - mean * mean;
        red[0] = mean; red[1] = rsqrtf(var + 1e-5f);
    }
    __syncthreads();
    float mean = red[0], rstd = red[1];
    for (int j = 0; j < 4; ++j) {
        int c = t * 4 + j;
        float hv = (v[j] - mean) * rstd * load_in(g2, c, f32) + load_in(be2, c, f32);
        h2t[tidx(row, c, 32)] = f2bf(hv);
    }
}

// ---------------- flash attention (pair-balanced + 2-stream j-split ILP) ----
// qk: [4096][2048] rowmajor (Q cols 0..1023, K cols 1024..2047)
// vt: [b*16+h][64 d][2048 s] planes (V transposed, by QKV gemm)
// Block = 128 thr (2 waves) owning 32 Q-rows; column pair (31-px, px).
// Per column, j-tiles split into two INDEPENDENT online-softmax streams
// (even j -> A, odd j -> B) merged at the end -> 2x ILP on the serial chain.
__global__ __launch_bounds__(128) void flash_kernel(
        const u16* __restrict__ qk, const u16* __restrict__ vt,
        u16* __restrict__ attn_t) {
    __shared__ __align__(16) u16 Ps[64 * 72];     // 2 waves x 2 streams x 16 rows
    int t = threadIdx.x;
    int px = blockIdx.x & 15, rh = blockIdx.x >> 4;
    int b = blockIdx.y >> 4, h = blockIdx.y & 15;
    int wid = t >> 6, lane = t & 63, quad = lane >> 4, l16 = lane & 15;
    int g = rh * 2 + wid;                         // global 16-row group 0..3
    const size_t seq_base = (size_t)b * TSEQ;
    const u16* vplane = vt + (size_t)(b * 16 + h) * 64 * 2048;
    const f32x4 fz = {0.f, 0.f, 0.f, 0.f};

    for (int half = 0; half < 2; ++half) {
        int tq = half ? px : (31 - px);

        bf16x8 aq[2];
        for (int kit = 0; kit < 2; ++kit)
            aq[kit] = *reinterpret_cast<const bf16x8*>(
                &qk[(seq_base + tq * 64 + g * 16 + l16) * 2048 + h * 64 + kit * 32 + quad * 8]);

        float mA[4], lA[4], mB[4], lB[4];
        f32x4 oA[4], oB[4];
        for (int r = 0; r < 4; ++r) {
            mA[r] = NEG_BIG; lA[r] = 0.f; mB[r] = NEG_BIG; lB[r] = 0.f;
        }
        for (int nt = 0; nt < 4; ++nt) { oA[nt] = fz; oB[nt] = fz; }

        // one j-tile into a given stream's state; st selects the Ps stripe
        auto tile = [&](int j, int domask, float (&m_run)[4], float (&l_run)[4],
                        f32x4 (&o)[4], int st) {
            f32x4 sa[4];
            for (int nt = 0; nt < 4; ++nt) sa[nt] = fz;
            for (int kit = 0; kit < 2; ++kit)
                for (int nt = 0; nt < 4; ++nt) {
                    bf16x8 bk = *reinterpret_cast<const bf16x8*>(
                        &qk[(seq_base + j * 64 + nt * 16 + l16) * 2048 + 1024 + h * 64 + kit * 32 + quad * 8]);
                    sa[nt] = __builtin_amdgcn_mfma_f32_16x16x32_bf16(aq[kit], bk, sa[nt], 0, 0, 0);
                }
            int qbase = tq * 64 + g * 16 + quad * 4;
            int sbase = j * 64 + l16;
            float p_val[4][4];
            for (int r = 0; r < 4; ++r) {
                float sv[4];
                float mx = NEG_BIG;
                for (int nt = 0; nt < 4; ++nt) {
                    float xv = sa[nt][r] * 0.03125f;   // D^-0.5 = 1/32
                    if (domask && (sbase + nt * 16 > qbase + r)) xv = NEG_BIG;
                    sv[nt] = xv;
                    mx = fmaxf(mx, xv);
                }
                for (int m = 1; m < 16; m <<= 1) mx = fmaxf(mx, __shfl_xor(mx, m));
                float mnew = fmaxf(m_run[r], mx);
                float alpha = __expf(m_run[r] - mnew);
                m_run[r] = mnew;
                float rs = 0.f;
                for (int nt = 0; nt < 4; ++nt) {
                    float pv = __expf(sv[nt] - mnew);
                    p_val[nt][r] = pv;
                    rs += pv;
                }
                for (int m = 1; m < 16; m <<= 1) rs += __shfl_xor(rs, m);
                l_run[r] = l_run[r] * alpha + rs;
                for (int nt = 0; nt < 4; ++nt) o[nt][r] *= alpha;
            }
            // stripe = (wid*2+st)*16 rows; same-wave LDS ordering, no barrier
            int srow = (wid * 2 + st) * 16;
            for (int nt = 0; nt < 4; ++nt)
                for (int r = 0; r < 4; ++r)
                    Ps[(srow + quad * 4 + r) * 72 + nt * 16 + l16] = f2bf(p_val[nt][r]);
            for (int kit = 0; kit < 2; ++kit) {
                bf16x8 ap = *reinterpret_cast<const bf16x8*>(
                    &Ps[(srow + l16) * 72 + kit * 32 + quad * 8]);
                for (int nt = 0; nt < 4; ++nt) {
                    bf16x8 bv = *reinterpret_cast<const bf16x8*>(
                        &vplane[(size_t)(nt * 16 + l16) * 2048 + j * 64 + kit * 32 + quad * 8]);
                    o[nt] = __builtin_amdgcn_mfma_f32_16x16x32_bf16(ap, bv, o[nt], 0, 0, 0);
                }
            }
        };

        // interleave two independent streams over the mask-free tiles 0..tq-1
        int j = 0;
        for (; j + 1 < tq; j += 2) {
            tile(j, 0, mA, lA, oA, 0);
            tile(j + 1, 0, mB, lB, oB, 1);
        }
        if (j < tq) {                 // odd tq: one full tile left + diagonal
            tile(j, 0, mA, lA, oA, 0);
            tile(tq, 1, mB, lB, oB, 1);
        } else {                      // even tq: diagonal only
            tile(tq, 1, mA, lA, oA, 0);
        }

        // merge streams and write
        for (int r = 0; r < 4; ++r) {
            float mm = fmaxf(mA[r], mB[r]);
            float a0 = __expf(mA[r] - mm), a1 = __expf(mB[r] - mm);
            float li = 1.f / (a0 * lA[r] + a1 * lB[r]);
            int trow = (int)seq_base + tq * 64 + g * 16 + quad * 4 + r;
            for (int nt = 0; nt < 4; ++nt) {
                float val = (a0 * oA[nt][r] + a1 * oB[nt][r]) * li;
                attn_t[tidx(trow, h * 64 + nt * 16 + l16, 32)] = f2bf(val);
            }
        }
    }
}

// ---------------- launch ----------------
// sk layout (ws elems, 1M=1<<20; needs >= 58MB = 29M elems):
//  [ 0, 8M): qk rowmajor -> Pp_oproj (4M f32) -> a1 [0,16M)
//  [ 8,12M): vt planes -> a1 part
//  [12,16M): attn_t (tiled) -> a1 part
//  [16,20M): W1t -> Pp_ffn part ([16,24M) as 4M f32)
//  [20,24M): h (LN1) -> Wot [20,21M) -> h2 (LN2 out) -> Pp_ffn part
//  [24,27M): Wtq -> W2t [24,28M)
//  [28M]:    dtype flag
extern "C" void kernel_launch(void* const* d_in, const int* in_sizes, int n_in,
                              void* d_out, int out_size, void* d_ws, size_t ws_size,
                              hipStream_t stream) {
    const u16* x   = (const u16*)d_in[0];
    const u16* Wq  = (const u16*)d_in[1];
    const u16* Wk  = (const u16*)d_in[2];
    const u16* Wv  = (const u16*)d_in[3];
    const u16* Wo  = (const u16*)d_in[4];
    const u16* bo  = (const u16*)d_in[5];
    const u16* W1  = (const u16*)d_in[6];
    const u16* b1  = (const u16*)d_in[7];
    const u16* W2  = (const u16*)d_in[8];
    const u16* b2  = (const u16*)d_in[9];
    const u16* g1  = (const u16*)d_in[10];
    const u16* be1 = (const u16*)d_in[11];
    const u16* g2  = (const u16*)d_in[12];
    const u16* be2 = (const u16*)d_in[13];
    u16* out = (u16*)d_out;

    const size_t M1 = (size_t)1 << 20;
    u16* ws = (u16*)d_ws;
    bool sk = ws_size >= ((size_t)58 << 20);

    if (sk) {
        u16* qk   = ws;                 // [0,8M)
        u16* vt   = ws + 8 * M1;        // [8,12M)
        u16* attn = ws + 12 * M1;       // [12,16M)
        u16* W1t  = ws + 16 * M1;       // [16,20M)
        u16* h    = ws + 20 * M1;       // [20,24M) LN1 out
        u16* Wot  = ws + 20 * M1;       // [20,21M) after gemm0
        u16* h2   = ws + 20 * M1;       // [20,24M) LN2 out (after oproj)
        u16* Wtq  = ws + 24 * M1;       // [24,27M)
        u16* W2t  = ws + 24 * M1;       // [24,28M) after gemm0
        u16* a1   = ws;                 // [0,16M) after oproj
        float* PpO = reinterpret_cast<float*>(ws);            // [0,8M) as 4M f32
        float* PpF = reinterpret_cast<float*>(ws + 16 * M1);  // [16,24M) as 4M f32
        u16* fl   = ws + 28 * M1;

        detect_kernel<<<1, 64, 0, stream>>>(x, fl);

        // LN1 + QKV projection (Q,K rowmajor; V -> vt transposed planes)
        pack_qkv_kernel<<<1536, 256, 0, stream>>>(Wq, Wk, Wv, Wtq, fl);
        ln_kernel<<<NTOK, 256, 0, stream>>>(x, g1, be1, h, fl);
        gemm_t<0, 64><<<dim3(48, 32), 256, 0, stream>>>(
            h, Wtq, qk, vt, nullptr, nullptr, 3072, 1024, 8, 0, fl);

        // Wo repack (h dead)
        transpose_tiled_kernel<<<dim3(16, 16), 256, 0, stream>>>(Wo, Wot, 32, fl);

        // attention (pair-balanced + 2-stream ILP)
        flash_kernel<<<dim3(32, 32), 128, 0, stream>>>(qk, vt, attn);

        // out-proj split-K (qk dead -> PpO) + fused fin+LN2
        zero_f32_kernel<<<4096, 256, 0, stream>>>(PpO);
        gemm_sk_t<2, 8, 64><<<dim3(16, 32, 4), 256, 0, stream>>>(attn, Wot, PpO, 1024, 1024);
        oproj_fin_ln2_kernel<<<4096, 256, 0, stream>>>(PpO, bo, x, g2, be2, out, h2, fl);

        // weight repacks
        transpose_tiled_kernel<<<dim3(16, 64), 256, 0, stream>>>(W2, W2t, 128, fl);
        transpose_tiled_kernel<<<dim3(64, 16), 256, 0, stream>>>(W1, W1t, 32, fl);

        // FFN up: single M=4096 dispatch, 2048 blocks
        gemm_t<2, 64><<<dim3(64, 32), 256, 0, stream>>>(
            h2, W1t, a1, nullptr, b1, nullptr, 4096, 1024, 1 | 4, 0, fl);
        // FFN down: single M=4096 split-K chain
        zero_f32_kernel<<<4096, 256, 0, stream>>>(PpF);
        gemm_sk_t<0, 32, 64><<<dim3(16, 32, 4), 256, 0, stream>>>(a1, W2t, PpF, 1024, 4096);
        ffn_fin_kernel<<<4096, 256, 0, stream>>>(PpF, b2, out, 0, fl);
    } else {
        // fallback (<58MB): chunked non-sk path, 40MB layout
        u16* qk   = ws;                 // [0,8M)
        u16* vt   = ws + 8 * M1;        // [8,12M)
        u16* h    = ws + 12 * M1;       // [12,16M)
        u16* attn = ws + 12 * M1;
        u16* h2   = ws + 12 * M1;
        u16* Wtq  = ws + 16 * M1;       // [16,19M)
        u16* Wot  = ws + 16 * M1;
        u16* W1t  = ws + 16 * M1;       // [16,20M)
        u16* W2t  = ws;                 // [0,4M) after flash
        u16* a1   = ws + 4 * M1;        // [4,12M) per 2048-row chunk
        u16* fl   = ws + 20 * M1;

        detect_kernel<<<1, 64, 0, stream>>>(x, fl);
        pack_qkv_kernel<<<1536, 256, 0, stream>>>(Wq, Wk, Wv, Wtq, fl);
        ln_kernel<<<NTOK, 256, 0, stream>>>(x, g1, be1, h, fl);
        gemm_t<0, 64><<<dim3(48, 32), 256, 0, stream>>>(
            h, Wtq, qk, vt, nullptr, nullptr, 3072, 1024, 8, 0, fl);
        transpose_tiled_kernel<<<dim3(16, 16), 256, 0, stream>>>(Wo, Wot, 32, fl);
        flash_kernel<<<dim3(32, 32), 128, 0, stream>>>(qk, vt, attn);
        gemm_t<1, 128><<<dim3(8, 32), 256, 0, stream>>>(
            attn, Wot, out, nullptr, bo, x, 1024, 1024, 2, 0, fl);
        transpose_tiled_kernel<<<dim3(16, 64), 256, 0, stream>>>(W2, W2t, 128, fl);
        transpose_tiled_kernel<<<dim3(64, 16), 256, 0, stream>>>(W1, W1t, 32, fl);
        ln_kernel<<<NTOK, 256, 0, stream>>>(out, g2, be2, h2, fl);
        gemm_t<2, 64><<<dim3(64, 16), 256, 0, stream>>>(
            h2, W1t, a1, nullptr, b1, nullptr, 4096, 1024, 1 | 4, 0, fl);
        gemm_t<4, 128><<<dim3(8, 16), 256, 0, stream>>>(
            a1, W2t, out, nullptr, b2, out, 1024, 4096, 2, 0, fl);
        gemm_t<3, 64><<<dim3(64, 16), 256, 0, stream>>>(
            h2 + (size_t)2 * M1, W1t, a1, nullptr, b1, nullptr, 4096, 1024, 1 | 4, 0, fl);
        gemm_t<5, 128><<<dim3(8, 16), 256, 0, stream>>>(
            a1, W2t, out, nullptr, b2, out, 1024, 4096, 2, 2048, fl);
    }
}